// Round 4
// baseline (543.455 us; speedup 1.0000x reference)
//
#include <hip/hip_runtime.h>

// ---------------------------------------------------------------------------
// QueryConditionedTransportScorerV3 on MI355X (gfx950)
// Q=64 W=16 A=64 D=H=512.
//   fused@rw1 = Ya[w,a] + Yq[q] + [a*q ; |a-q|+c] @ (rg*rw1)[1024:2048] (MFMA)
//   h = rstd*(sum - mu*S1) + (rb1 + rb@rw1); gelu; @rw2; softmax+entropy fused
// Round 4: main kernel re-decomposed — 1024-thr block, 16 waves x (64r x 32c),
//   acc[4][2]=32 regs fits the 128-reg cap at 4 waves/SIMD (kills the scratch
//   spills that produced 235 MB WRITE_SIZE). Full-K 128 KB LDS, single build.
// ---------------------------------------------------------------------------

#define DEV static __device__ __forceinline__

typedef __attribute__((ext_vector_type(8))) __bf16 bf16x8;
typedef __attribute__((ext_vector_type(4))) float f32x4;

DEV unsigned short f2bf(float f) {
  unsigned u = __builtin_bit_cast(unsigned, f);
  u = (u + 0x7fffu + ((u >> 16) & 1u)) >> 16;
  return (unsigned short)u;
}

// branch-free erf (Abramowitz-Stegun 7.1.26, |err| <= 1.5e-7)
DEV float gelu_fast(float x) {
  const float y = x * 0.70710678118654752f;
  const float z = fabsf(y);
  const float t = __fdividef(1.0f, 1.0f + 0.3275911f * z);
  float p = 1.061405429f;
  p = p * t - 1.453152027f;
  p = p * t + 1.421413741f;
  p = p * t - 0.284496736f;
  p = p * t + 0.254829592f;
  const float e = 1.0f - p * t * __expf(-z * z);
  const float erfv = copysignf(e, y);
  return 0.5f * x * (1.0f + erfv);
}

// ---- ws layout (float offsets) --------------------------------------------
#define OFF_XQ    0          // 64*512
#define OFF_XA    32768      // 1024*512
#define OFF_XC    557056     // 16*1024
#define OFF_HQ    573440     // 64*512
#define OFF_HA    606208     // 1024*512
#define OFF_HC    1130496    // 16*512
#define OFF_QH    1138688    // 64*512
#define OFF_AHH   1171456    // 1024*512
#define OFF_CHH   1695744    // 16*512
#define OFF_YA    OFF_XA
#define OFF_YQ    OFF_XQ
#define OFF_WAYA  1703936    // 512*512
#define OFF_WQYQ  1966080    // 512*512
#define OFF_BYA   2228224    // 512
#define OFF_BYQ   2228736    // 512
#define OFF_S1    2229248    // 512
#define OFF_B1    2229760    // 512
#define OFF_WT    2230272    // 524288 bf16 = 262144 f32  (total 2492416 f32)

// ======================== P0: wide prep kernel ==============================
// roles: [0,128) WT transpose | [128,144) S1/B1 | [144,208) q pool+LN
//        [208,336) a LN (8 rows/blk, wave per row) | [336,352) c concat+LN
__global__ __launch_bounds__(512) void pre0_kernel(
    const float* __restrict__ qa, const float* __restrict__ qm,
    const float* __restrict__ ca, const float* __restrict__ csum,
    const float* __restrict__ ectx,
    const float* __restrict__ qg, const float* __restrict__ qb,
    const float* __restrict__ ag, const float* __restrict__ ab,
    const float* __restrict__ cg, const float* __restrict__ cb,
    const float* __restrict__ rw1, const float* __restrict__ rg,
    const float* __restrict__ rb, float* __restrict__ ws) {
  __shared__ float sh[4160];   // 64*65 floats, reused per role
  const int b = blockIdx.x, tid = threadIdx.x, l = tid & 63, wv = tid >> 6;

  if (b < 128) {
    // ---- WT[n][k2] = rg[1024+k2] * rw1[1024+k2][n]
    unsigned short* WT = (unsigned short*)(ws + OFF_WT);
    float (*t)[65] = (float(*)[65])sh;
    const int kt = (b >> 3) << 6;
    const int ct = (b & 7) << 6;
    for (int idx = tid; idx < 4096; idx += 512) {
      const int r = idx >> 6, c = idx & 63;
      t[r][c] = rg[1024 + kt + r] * rw1[(1024 + kt + r) * 512 + ct + c];
    }
    __syncthreads();
    for (int idx = tid; idx < 4096; idx += 512) {
      const int c = idx >> 6, r = idx & 63;
      WT[(ct + c) * 1024 + kt + r] = f2bf(t[r][c]);
    }
  } else if (b < 144) {
    // ---- S1[n] += sum rg[k]*rw1[k][n]; B1[n] += sum rb[k]*rw1[k][n]
    const int kc = (b - 128) << 7;
    float s0 = 0.f, s1 = 0.f, b0 = 0.f, b1v = 0.f;
    for (int k = kc; k < kc + 128; k += 2) {
      const float wa = rw1[(k << 9) + tid];
      const float wb = rw1[((k + 1) << 9) + tid];
      s0 += rg[k] * wa; b0 += rb[k] * wa;
      s1 += rg[k + 1] * wb; b1v += rb[k + 1] * wb;
    }
    atomicAdd(ws + OFF_S1 + tid, s0 + s1);
    atomicAdd(ws + OFF_B1 + tid, b0 + b1v);
  } else if (b < 208) {
    // ---- q path: masses -> pool -> LN -> xq
    const int q = b - 144;
    if (wv == 0) {
      float m = fmaxf(qm[(q << 6) + l], 0.f);
      sh[l] = m;
      float s = m;
#pragma unroll
      for (int off = 1; off < 64; off <<= 1) s += __shfl_xor(s, off);
      if (l == 0) sh[64] = 1.0f / fmaxf(s, 1e-8f);
    }
    __syncthreads();
    const float sinv = sh[64];
    const float* qaq = qa + (q << 15) + tid;
    float v0 = 0.f, v1 = 0.f, v2 = 0.f, v3 = 0.f;
#pragma unroll 4
    for (int a = 0; a < 64; a += 4) {
      v0 += sh[a] * qaq[a << 9];
      v1 += sh[a + 1] * qaq[(a + 1) << 9];
      v2 += sh[a + 2] * qaq[(a + 2) << 9];
      v3 += sh[a + 3] * qaq[(a + 3) << 9];
    }
    const float v = (v0 + v1 + v2 + v3) * sinv;
    float s = v, ss = v * v;
#pragma unroll
    for (int off = 1; off < 64; off <<= 1) {
      s += __shfl_xor(s, off); ss += __shfl_xor(ss, off);
    }
    if (l == 0) { sh[128 + wv] = s; sh[136 + wv] = ss; }
    __syncthreads();
    float st = 0.f, sst = 0.f;
#pragma unroll
    for (int i = 0; i < 8; ++i) { st += sh[128 + i]; sst += sh[136 + i]; }
    const float mu = st * (1.0f / 512.0f);
    const float rstd = rsqrtf(sst * (1.0f / 512.0f) - mu * mu + 1e-5f);
    ws[OFF_XQ + (q << 9) + tid] = (v - mu) * rstd * qg[tid] + qb[tid];
  } else if (b < 336) {
    // ---- a path LN: wave per row
    const int row = ((b - 208) << 3) + wv;
    const float* crow = ca + (row << 9);
    float x[8];
    float s = 0.f, ss = 0.f;
#pragma unroll
    for (int i = 0; i < 8; ++i) {
      x[i] = crow[l + (i << 6)];
      s += x[i]; ss += x[i] * x[i];
    }
#pragma unroll
    for (int off = 1; off < 64; off <<= 1) {
      s += __shfl_xor(s, off); ss += __shfl_xor(ss, off);
    }
    const float mu = s * (1.0f / 512.0f);
    const float rstd = rsqrtf(ss * (1.0f / 512.0f) - mu * mu + 1e-5f);
#pragma unroll
    for (int i = 0; i < 8; ++i) {
      const int k = l + (i << 6);
      ws[OFF_XA + (row << 9) + k] = (x[i] - mu) * rstd * ag[k] + ab[k];
    }
  } else {
    // ---- c path: concat + LN (din=1024)
    const int w = b - 336;
    const float v0 = csum[(w << 9) + tid];
    const float v1 = ectx[(w << 9) + tid];
    float s = v0 + v1, ss = v0 * v0 + v1 * v1;
#pragma unroll
    for (int off = 1; off < 64; off <<= 1) {
      s += __shfl_xor(s, off); ss += __shfl_xor(ss, off);
    }
    if (l == 0) { sh[wv] = s; sh[8 + wv] = ss; }
    __syncthreads();
    float st = 0.f, sst = 0.f;
#pragma unroll
    for (int i = 0; i < 8; ++i) { st += sh[i]; sst += sh[8 + i]; }
    const float mu = st * (1.0f / 1024.0f);
    const float rstd = rsqrtf(sst * (1.0f / 1024.0f) - mu * mu + 1e-5f);
    ws[OFF_XC + (w << 10) + tid] = (v0 - mu) * rstd * cg[tid] + cb[tid];
    ws[OFF_XC + (w << 10) + 512 + tid] =
        (v1 - mu) * rstd * cg[512 + tid] + cb[512 + tid];
  }
}

// ======================== generic FC tile ===================================
// 256 threads: c = ct*128 + tid%128, rg = tid/128; RPT rows per thread.
// out[r][c] = (gelu?)( bias[c] + sum_k A[r][k] * (s?s[k]:1) * W[k][c] )
template <int RPT, bool GELU, bool HAS_S, bool SROW>
DEV void fc_tile(const float* __restrict__ A, int lda,
                 const float* __restrict__ W, const float* __restrict__ bias,
                 const float* __restrict__ s, float* __restrict__ O,
                 int K, int rt, int ct, int tid) {
  const int c = (ct << 7) + (tid & 127);
  const int rg = tid >> 7;
  const int r0 = SROW ? 0 : rt * (2 * RPT) + rg * RPT;
  float acc[RPT];
#pragma unroll
  for (int j = 0; j < RPT; ++j) acc[j] = 0.f;
#pragma unroll 2
  for (int k0 = 0; k0 < K; k0 += 4) {
    float w0 = W[(k0 + 0) * 512 + c];
    float w1 = W[(k0 + 1) * 512 + c];
    float w2 = W[(k0 + 2) * 512 + c];
    float w3 = W[(k0 + 3) * 512 + c];
    if (HAS_S) {
      w0 *= s[k0]; w1 *= s[k0 + 1]; w2 *= s[k0 + 2]; w3 *= s[k0 + 3];
    }
#pragma unroll
    for (int j = 0; j < RPT; ++j) {
      const float4 xv = *(const float4*)(A + (r0 + j) * lda + k0);
      acc[j] = fmaf(xv.w, w3, fmaf(xv.z, w2, fmaf(xv.y, w1, fmaf(xv.x, w0, acc[j]))));
    }
  }
  const float bv = bias ? bias[c] : 0.f;
#pragma unroll
  for (int j = 0; j < RPT; ++j) {
    float o = acc[j] + bv;
    if (GELU) o = gelu_fast(o);
    O[(r0 + j) * 512 + c] = o;
  }
}

// ---- FC1: layer1 (a/q/c) + Waya/Wqyq + bya/byq -----------------------------
__global__ __launch_bounds__(256) void fc1_kernel(
    float* __restrict__ ws,
    const float* __restrict__ aw1, const float* __restrict__ ab1,
    const float* __restrict__ qw1, const float* __restrict__ qb1,
    const float* __restrict__ cw1, const float* __restrict__ cb1,
    const float* __restrict__ aw2, const float* __restrict__ qw2,
    const float* __restrict__ ab2, const float* __restrict__ qb2,
    const float* __restrict__ rw1, const float* __restrict__ rg) {
  const int b = blockIdx.x, tid = threadIdx.x;
  if (b < 128) {           // a layer1: 1024 rows
    fc_tile<16, true, false, false>(ws + OFF_XA, 512, aw1, ab1, nullptr,
                                    ws + OFF_HA, 512, b >> 2, b & 3, tid);
  } else if (b < 136) {    // q layer1: 64 rows
    const int bb = b - 128;
    fc_tile<16, true, false, false>(ws + OFF_XQ, 512, qw1, qb1, nullptr,
                                    ws + OFF_HQ, 512, bb >> 2, bb & 3, tid);
  } else if (b < 140) {    // c layer1: 16 rows, K=1024
    fc_tile<8, true, false, false>(ws + OFF_XC, 1024, cw1, cb1, nullptr,
                                   ws + OFF_HC, 1024, 0, b - 136, tid);
  } else if (b < 204) {    // Waya[k][n] = sum_j aw2[k][j]*rg[j]*rw1[j][n]
    const int bb = b - 140;
    fc_tile<16, false, true, false>(aw2, 512, rw1, nullptr, rg,
                                    ws + OFF_WAYA, 512, bb >> 2, bb & 3, tid);
  } else if (b < 268) {    // Wqyq[k][n] = sum_j qw2[k][j]*rg[512+j]*rw1hi[j][n]
    const int bb = b - 204;
    fc_tile<16, false, true, false>(qw2, 512, rw1 + 512 * 512, nullptr, rg + 512,
                                    ws + OFF_WQYQ, 512, bb >> 2, bb & 3, tid);
  } else if (b < 272) {    // bya[n] = sum_j ab2[j]*rg[j]*rw1[j][n]
    fc_tile<1, false, true, true>(ab2, 0, rw1, nullptr, rg,
                                  ws + OFF_BYA, 512, 0, b - 268, tid);
  } else {                 // byq[n] = sum_j qb2[j]*rg[512+j]*rw1hi[j][n]
    fc_tile<1, false, true, true>(qb2, 0, rw1 + 512 * 512, nullptr, rg + 512,
                                  ws + OFF_BYQ, 512, 0, b - 272, tid);
  }
}

// ---- FC2: layer2 (ahh/qh/chh) + Ya/Yq (via Waya/Wqyq) ----------------------
__global__ __launch_bounds__(256) void fc2_kernel(
    float* __restrict__ ws,
    const float* __restrict__ aw2, const float* __restrict__ ab2,
    const float* __restrict__ qw2, const float* __restrict__ qb2,
    const float* __restrict__ cw2, const float* __restrict__ cb2) {
  const int b = blockIdx.x, tid = threadIdx.x;
  if (b < 128) {           // ahh = ha @ aw2 + ab2
    fc_tile<16, false, false, false>(ws + OFF_HA, 512, aw2, ab2, nullptr,
                                     ws + OFF_AHH, 512, b >> 2, b & 3, tid);
  } else if (b < 256) {    // Ya = ha @ Waya + bya
    const int bb = b - 128;
    fc_tile<16, false, false, false>(ws + OFF_HA, 512, ws + OFF_WAYA,
                                     ws + OFF_BYA, nullptr, ws + OFF_YA, 512,
                                     bb >> 2, bb & 3, tid);
  } else if (b < 264) {    // qh = hq @ qw2 + qb2
    const int bb = b - 256;
    fc_tile<16, false, false, false>(ws + OFF_HQ, 512, qw2, qb2, nullptr,
                                     ws + OFF_QH, 512, bb >> 2, bb & 3, tid);
  } else if (b < 272) {    // Yq = hq @ Wqyq + byq
    const int bb = b - 264;
    fc_tile<16, false, false, false>(ws + OFF_HQ, 512, ws + OFF_WQYQ,
                                     ws + OFF_BYQ, nullptr, ws + OFF_YQ, 512,
                                     bb >> 2, bb & 3, tid);
  } else {                 // chh = hc @ cw2 + cb2
    fc_tile<8, false, false, false>(ws + OFF_HC, 512, cw2, cb2, nullptr,
                                    ws + OFF_CHH, 512, 0, b - 272, tid);
  }
}

// ---------------------------- main fused kernel -----------------------------
// 1 block per (q,w), 1024 threads = 16 waves. Full-K 64x1024 bf16 pair tile
// in 128 KB LDS (frag order). Wave wv -> 64 rows x cols [wv*32, wv*32+32):
// acc[4][2] = 32 regs -> fits 128-reg cap at 4 waves/SIMD (no spill).
__global__ __launch_bounds__(1024, 4) void main_kernel(
    const float* __restrict__ AH, const float* __restrict__ QH,
    const float* __restrict__ CH, const unsigned short* __restrict__ WT,
    const float* __restrict__ Ya, const float* __restrict__ Yq,
    const float* __restrict__ S1, const float* __restrict__ B1,
    const float* __restrict__ rb1, const float* __restrict__ rw2,
    const float* __restrict__ rb2, const float* __restrict__ cmass,
    float* __restrict__ out) {
  extern __shared__ char smem_raw[];
  float* qs = (float*)smem_raw;          // 512
  float* cs = qs + 512;                  // 512
  float* s1_s = cs + 512;                // 64
  float* s2_s = s1_s + 64;               // 64
  float* rel_s = s2_s + 64;              // 64
  float* misc = rel_s + 64;              // 2 (+pad to 5120 B)
  uint4* apv = (uint4*)(smem_raw + 5120);  // 128 KB: [ks(32)][fr(4)][l(64)]

  const int tid = threadIdx.x;
  const int l = tid & 63;
  const int wv = tid >> 6;               // 0..15
  const int q = blockIdx.x >> 4;
  const int w = blockIdx.x & 15;

  if (tid < 512) qs[tid] = QH[(q << 9) + tid];
  else cs[tid - 512] = CH[(w << 9) + (tid - 512)];
  if (tid < 64) { s1_s[tid] = 0.f; s2_s[tid] = 0.f; rel_s[tid] = 0.f; }
  __syncthreads();

  // ---- build pair matrix in MFMA-fragment order + fold LN stats ----------
  // thread: row rloc = ((wv&3)<<4)+(l&15); k-offset kh = (l>>4)*8;
  // ks = (wv>>2) + 4*i, i in [0,8)  -> all 32 ks covered.
  const int rloc = ((wv & 3) << 4) + (l & 15);
  const float* arow = AH + (((w << 6) + rloc) << 9);
  const int kh = (l >> 4) << 3;
  const int par = wv >> 2;               // 0..3
  float s1a = 0.f, s2a = 0.f;

#pragma unroll 2
  for (int i = 0; i < 8; ++i) {
    const int ks = par + (i << 2);
    const int kb = (ks << 5) + kh;       // k2 in [0,1024)
    const int ka = kb & 511;
    const float4 a0 = *(const float4*)(arow + ka);
    const float4 a1 = *(const float4*)(arow + ka + 4);
    const float4 q0 = *(const float4*)(qs + ka);
    const float4 q1 = *(const float4*)(qs + ka + 4);
    const float av[8] = {a0.x, a0.y, a0.z, a0.w, a1.x, a1.y, a1.z, a1.w};
    const float qv[8] = {q0.x, q0.y, q0.z, q0.w, q1.x, q1.y, q1.z, q1.w};
    float vv[8];
    if (kb < 512) {          // segment: a*q  (also accumulate a-seg stats)
#pragma unroll
      for (int j = 0; j < 8; ++j) {
        const float aq = av[j] * qv[j];
        vv[j] = aq;
        s1a += av[j] + aq;
        s2a += av[j] * av[j] + aq * aq;
      }
    } else {                 // segment: |a-q| + c
      const float4 c0 = *(const float4*)(cs + ka);
      const float4 c1 = *(const float4*)(cs + ka + 4);
      const float cv[8] = {c0.x, c0.y, c0.z, c0.w, c1.x, c1.y, c1.z, c1.w};
#pragma unroll
      for (int j = 0; j < 8; ++j) {
        const float dd = fabsf(av[j] - qv[j]) + cv[j];
        vv[j] = dd;
        s1a += dd;
        s2a += dd * dd;
      }
    }
    union { unsigned short us[8]; uint4 u4; } pk;
#pragma unroll
    for (int j = 0; j < 8; ++j) pk.us[j] = f2bf(vv[j]);
    apv[(ks << 8) + ((wv & 3) << 6) + l] = pk.u4;
  }

  // fold per-thread stats into per-row LDS totals
  s1a += __shfl_xor(s1a, 16); s1a += __shfl_xor(s1a, 32);
  s2a += __shfl_xor(s2a, 16); s2a += __shfl_xor(s2a, 32);
  if ((l >> 4) == 0) {
    atomicAdd(&s1_s[rloc], s1a);
    atomicAdd(&s2_s[rloc], s2a);
  }
  if (wv == 0) {  // q-segment stats (shared by all rows)
    float sq = 0.f, sqq = 0.f;
#pragma unroll
    for (int it = 0; it < 8; ++it) {
      const float vq = qs[l + (it << 6)];
      sq += vq; sqq += vq * vq;
    }
#pragma unroll
    for (int off = 1; off < 64; off <<= 1) {
      sq += __shfl_xor(sq, off); sqq += __shfl_xor(sqq, off);
    }
    if (l == 0) { misc[0] = sq; misc[1] = sqq; }
  }
  __syncthreads();

  // ---- MFMA: wave wv owns cols [wv*32, wv*32+32), K = 1024 ----------------
  f32x4 acc[4][2] = {};
  const int ncb = (wv << 5) + (l & 15);
  const unsigned short* wbase = WT + ncb * 1024 + kh;
#pragma unroll 8
  for (int ks = 0; ks < 32; ++ks) {
    bf16x8 bfr[2], afr[4];
#pragma unroll
    for (int cf = 0; cf < 2; ++cf)
      bfr[cf] = __builtin_bit_cast(
          bf16x8, *(const uint4*)(wbase + (cf << 14) + (ks << 5)));
#pragma unroll
    for (int fr = 0; fr < 4; ++fr)
      afr[fr] = __builtin_bit_cast(bf16x8, apv[(ks << 8) + (fr << 6) + l]);
#pragma unroll
    for (int fr = 0; fr < 4; ++fr)
#pragma unroll
      for (int cf = 0; cf < 2; ++cf)
        acc[fr][cf] = __builtin_amdgcn_mfma_f32_16x16x32_bf16(
            afr[fr], bfr[cf], acc[fr][cf], 0, 0, 0);
  }

  // ---- epilogue: LN-fold + gelu + dot(rw2) -> per-row relevance -----------
  {
    const float sqt = misc[0], sqqt = misc[1];
    float yqv[2], s1c[2], b1c[2], w2c[2];
#pragma unroll
    for (int cf = 0; cf < 2; ++cf) {
      const int n = ncb + (cf << 4);
      yqv[cf] = Yq[(q << 9) + n];
      s1c[cf] = S1[n];
      b1c[cf] = B1[n] + rb1[n];
      w2c[cf] = rw2[n];
    }
    const float* yab = Ya + (w << 15) + ncb;
    const int rsub = (l >> 4) << 2;
#pragma unroll
    for (int fr = 0; fr < 4; ++fr) {
#pragma unroll
      for (int j = 0; j < 4; ++j) {
        const int r = (fr << 4) + rsub + j;
        const float s1r = s1_s[r] + sqt;
        const float s2r = s2_s[r] + sqqt;
        const float mu = s1r * (1.0f / 2048.0f);
        const float rs = rsqrtf(s2r * (1.0f / 2048.0f) - mu * mu + 1e-5f);
        float rp = 0.f;
#pragma unroll
        for (int cf = 0; cf < 2; ++cf) {
          const float ya = yab[(r << 9) + (cf << 4)];
          const float hp = rs * (acc[fr][cf][j] + ya + yqv[cf] - mu * s1c[cf]) + b1c[cf];
          rp += gelu_fast(hp) * w2c[cf];
        }
        rp += __shfl_xor(rp, 1); rp += __shfl_xor(rp, 2);
        rp += __shfl_xor(rp, 4); rp += __shfl_xor(rp, 8);
        if ((l & 15) == 0) atomicAdd(&rel_s[r], rp);
      }
    }
  }
  __syncthreads();

  // ---- softmax over atoms + entropy (wave 0)
  if (tid < 64) {
    const float relv = rel_s[tid] + rb2[0];
    const float x = logf(fmaxf(cmass[(w << 6) + tid], 1e-8f)) + relv;
    float m = x;
#pragma unroll
    for (int off = 1; off < 64; off <<= 1) m = fmaxf(m, __shfl_xor(m, off));
    const float p = expf(x - m);
    float s = p;
#pragma unroll
    for (int off = 1; off < 64; off <<= 1) s += __shfl_xor(s, off);
    float mix = p / fmaxf(s, 1e-8f);
    float s2 = mix;
#pragma unroll
    for (int off = 1; off < 64; off <<= 1) s2 += __shfl_xor(s2, off);
    mix = mix / fmaxf(s2, 1e-8f);
    const float et = -mix * logf(fmaxf(mix, 1e-8f));
    float ent = et;
#pragma unroll
    for (int off = 1; off < 64; off <<= 1) ent += __shfl_xor(ent, off);
    out[(blockIdx.x << 6) + tid] = mix;                 // mixed[q][w][a]
    if (tid == 0) out[65536 + blockIdx.x] = ent;        // entropy[q][w]
  }
}

// ---------------------------------------------------------------------------
extern "C" void kernel_launch(void* const* d_in, const int* in_sizes, int n_in,
                              void* d_out, int out_size, void* d_ws, size_t ws_size,
                              hipStream_t stream) {
  (void)in_sizes; (void)n_in; (void)out_size; (void)ws_size;
  const float* q_atoms = (const float*)d_in[0];
  const float* q_mass  = (const float*)d_in[1];
  const float* c_atoms = (const float*)d_in[2];
  const float* c_mass  = (const float*)d_in[3];
  const float* c_sum   = (const float*)d_in[4];
  const float* e_ctx   = (const float*)d_in[5];
  const float* qg  = (const float*)d_in[6];  const float* qb  = (const float*)d_in[7];
  const float* qw1 = (const float*)d_in[8];  const float* qb1 = (const float*)d_in[9];
  const float* qw2 = (const float*)d_in[10]; const float* qb2 = (const float*)d_in[11];
  const float* ag  = (const float*)d_in[12]; const float* ab  = (const float*)d_in[13];
  const float* aw1 = (const float*)d_in[14]; const float* ab1 = (const float*)d_in[15];
  const float* aw2 = (const float*)d_in[16]; const float* ab2 = (const float*)d_in[17];
  const float* cg  = (const float*)d_in[18]; const float* cb  = (const float*)d_in[19];
  const float* cw1 = (const float*)d_in[20]; const float* cb1 = (const float*)d_in[21];
  const float* cw2 = (const float*)d_in[22]; const float* cb2 = (const float*)d_in[23];
  const float* rg  = (const float*)d_in[24]; const float* rb  = (const float*)d_in[25];
  const float* rw1 = (const float*)d_in[26]; const float* rb1 = (const float*)d_in[27];
  const float* rw2 = (const float*)d_in[28]; const float* rb2 = (const float*)d_in[29];

  float* ws = (float*)d_ws;
  float* out = (float*)d_out;

  hipMemsetAsync(ws + OFF_S1, 0, 1024 * sizeof(float), stream);  // S1+B1
  pre0_kernel<<<352, 512, 0, stream>>>(q_atoms, q_mass, c_atoms, c_sum, e_ctx,
                                       qg, qb, ag, ab, cg, cb, rw1, rg, rb, ws);
  fc1_kernel<<<276, 256, 0, stream>>>(ws, aw1, ab1, qw1, qb1, cw1, cb1,
                                      aw2, qw2, ab2, qb2, rw1, rg);
  fc2_kernel<<<276, 256, 0, stream>>>(ws, aw2, ab2, qw2, qb2, cw2, cb2);

  static const size_t MAIN_SMEM = 5120 + 131072;  // 136192 B (<= 160 KB/CU)
  hipFuncSetAttribute((const void*)main_kernel,
                      hipFuncAttributeMaxDynamicSharedMemorySize, (int)MAIN_SMEM);
  main_kernel<<<1024, 1024, MAIN_SMEM, stream>>>(
      ws + OFF_AHH, ws + OFF_QH, ws + OFF_CHH,
      (const unsigned short*)(ws + OFF_WT), ws + OFF_YA, ws + OFF_YQ,
      ws + OFF_S1, ws + OFF_B1, rb1, rw2, rb2, c_mass, out);
}

// Round 5
// 454.647 us; speedup vs baseline: 1.1953x; 1.1953x over previous
//
#include <hip/hip_runtime.h>

// ---------------------------------------------------------------------------
// QueryConditionedTransportScorerV3 on MI355X (gfx950)
// Q=64 W=16 A=64 D=H=512.
//   fused@rw1 = Ya[w,a] + Yq[q] + [a*q ; |a-q|+c] @ (rg*rw1)[1024:2048] (MFMA)
//   h = rstd*(sum - mu*S1) + (rb1 + rb@rw1); gelu; @rw2; softmax+entropy fused
// Round 5: main kernel software-pipelined — 4 K-chunks of 256, double-buffered
//   32KB LDS, T14-style async build (load-early / compute-late around MFMA),
//   k-tiled WT layout for 1KB-coalesced B loads. fc kernels: RPT=8, 2x grid.
// ---------------------------------------------------------------------------

#define DEV static __device__ __forceinline__

typedef __attribute__((ext_vector_type(8))) __bf16 bf16x8;
typedef __attribute__((ext_vector_type(4))) float f32x4;

DEV unsigned short f2bf(float f) {
  unsigned u = __builtin_bit_cast(unsigned, f);
  u = (u + 0x7fffu + ((u >> 16) & 1u)) >> 16;
  return (unsigned short)u;
}

// branch-free erf (Abramowitz-Stegun 7.1.26, |err| <= 1.5e-7)
DEV float gelu_fast(float x) {
  const float y = x * 0.70710678118654752f;
  const float z = fabsf(y);
  const float t = __fdividef(1.0f, 1.0f + 0.3275911f * z);
  float p = 1.061405429f;
  p = p * t - 1.453152027f;
  p = p * t + 1.421413741f;
  p = p * t - 0.284496736f;
  p = p * t + 0.254829592f;
  const float e = 1.0f - p * t * __expf(-z * z);
  const float erfv = copysignf(e, y);
  return 0.5f * x * (1.0f + erfv);
}

// ---- ws layout (float offsets) --------------------------------------------
#define OFF_XQ    0          // 64*512
#define OFF_XA    32768      // 1024*512
#define OFF_XC    557056     // 16*1024
#define OFF_HQ    573440     // 64*512
#define OFF_HA    606208     // 1024*512
#define OFF_HC    1130496    // 16*512
#define OFF_QH    1138688    // 64*512
#define OFF_AHH   1171456    // 1024*512
#define OFF_CHH   1695744    // 16*512
#define OFF_YA    OFF_XA
#define OFF_YQ    OFF_XQ
#define OFF_WAYA  1703936    // 512*512
#define OFF_WQYQ  1966080    // 512*512
#define OFF_BYA   2228224    // 512
#define OFF_BYQ   2228736    // 512
#define OFF_S1    2229248    // 512
#define OFF_B1    2229760    // 512
#define OFF_WT    2230272    // 524288 bf16 = 262144 f32  (total 2492416 f32)

// WT2 k-tiled layout: element (n, k2) at  (k2>>5)*16384 + n*32 + (k2&31)
// -> a wave's B-frag load (16 cols x 32 k) is one contiguous 1KB region.

// ======================== P0: wide prep kernel ==============================
// roles: [0,128) WT transpose | [128,144) S1/B1 | [144,208) q pool+LN
//        [208,336) a LN (8 rows/blk, wave per row) | [336,352) c concat+LN
__global__ __launch_bounds__(512) void pre0_kernel(
    const float* __restrict__ qa, const float* __restrict__ qm,
    const float* __restrict__ ca, const float* __restrict__ csum,
    const float* __restrict__ ectx,
    const float* __restrict__ qg, const float* __restrict__ qb,
    const float* __restrict__ ag, const float* __restrict__ ab,
    const float* __restrict__ cg, const float* __restrict__ cb,
    const float* __restrict__ rw1, const float* __restrict__ rg,
    const float* __restrict__ rb, float* __restrict__ ws) {
  __shared__ float sh[4160];   // 64*65 floats, reused per role
  const int b = blockIdx.x, tid = threadIdx.x, l = tid & 63, wv = tid >> 6;

  if (b < 128) {
    // ---- WT2[(k2>>5)][n][k2&31] = rg[1024+k2] * rw1[1024+k2][n]
    unsigned short* WT = (unsigned short*)(ws + OFF_WT);
    float (*t)[65] = (float(*)[65])sh;
    const int kt = (b >> 3) << 6;
    const int ct = (b & 7) << 6;
    for (int idx = tid; idx < 4096; idx += 512) {
      const int r = idx >> 6, c = idx & 63;
      t[r][c] = rg[1024 + kt + r] * rw1[(1024 + kt + r) * 512 + ct + c];
    }
    __syncthreads();
    for (int idx = tid; idx < 4096; idx += 512) {
      const int c = idx >> 6, r = idx & 63;
      const int n = ct + c, k2 = kt + r;
      WT[((k2 >> 5) << 14) + (n << 5) + (k2 & 31)] = f2bf(t[r][c]);
    }
  } else if (b < 144) {
    // ---- S1[n] += sum rg[k]*rw1[k][n]; B1[n] += sum rb[k]*rw1[k][n]
    const int kc = (b - 128) << 7;
    float s0 = 0.f, s1 = 0.f, b0 = 0.f, b1v = 0.f;
    for (int k = kc; k < kc + 128; k += 2) {
      const float wa = rw1[(k << 9) + tid];
      const float wb = rw1[((k + 1) << 9) + tid];
      s0 += rg[k] * wa; b0 += rb[k] * wa;
      s1 += rg[k + 1] * wb; b1v += rb[k + 1] * wb;
    }
    atomicAdd(ws + OFF_S1 + tid, s0 + s1);
    atomicAdd(ws + OFF_B1 + tid, b0 + b1v);
  } else if (b < 208) {
    // ---- q path: masses -> pool -> LN -> xq
    const int q = b - 144;
    if (wv == 0) {
      float m = fmaxf(qm[(q << 6) + l], 0.f);
      sh[l] = m;
      float s = m;
#pragma unroll
      for (int off = 1; off < 64; off <<= 1) s += __shfl_xor(s, off);
      if (l == 0) sh[64] = 1.0f / fmaxf(s, 1e-8f);
    }
    __syncthreads();
    const float sinv = sh[64];
    const float* qaq = qa + (q << 15) + tid;
    float v0 = 0.f, v1 = 0.f, v2 = 0.f, v3 = 0.f;
#pragma unroll 4
    for (int a = 0; a < 64; a += 4) {
      v0 += sh[a] * qaq[a << 9];
      v1 += sh[a + 1] * qaq[(a + 1) << 9];
      v2 += sh[a + 2] * qaq[(a + 2) << 9];
      v3 += sh[a + 3] * qaq[(a + 3) << 9];
    }
    const float v = (v0 + v1 + v2 + v3) * sinv;
    float s = v, ss = v * v;
#pragma unroll
    for (int off = 1; off < 64; off <<= 1) {
      s += __shfl_xor(s, off); ss += __shfl_xor(ss, off);
    }
    if (l == 0) { sh[128 + wv] = s; sh[136 + wv] = ss; }
    __syncthreads();
    float st = 0.f, sst = 0.f;
#pragma unroll
    for (int i = 0; i < 8; ++i) { st += sh[128 + i]; sst += sh[136 + i]; }
    const float mu = st * (1.0f / 512.0f);
    const float rstd = rsqrtf(sst * (1.0f / 512.0f) - mu * mu + 1e-5f);
    ws[OFF_XQ + (q << 9) + tid] = (v - mu) * rstd * qg[tid] + qb[tid];
  } else if (b < 336) {
    // ---- a path LN: wave per row
    const int row = ((b - 208) << 3) + wv;
    const float* crow = ca + (row << 9);
    float x[8];
    float s = 0.f, ss = 0.f;
#pragma unroll
    for (int i = 0; i < 8; ++i) {
      x[i] = crow[l + (i << 6)];
      s += x[i]; ss += x[i] * x[i];
    }
#pragma unroll
    for (int off = 1; off < 64; off <<= 1) {
      s += __shfl_xor(s, off); ss += __shfl_xor(ss, off);
    }
    const float mu = s * (1.0f / 512.0f);
    const float rstd = rsqrtf(ss * (1.0f / 512.0f) - mu * mu + 1e-5f);
#pragma unroll
    for (int i = 0; i < 8; ++i) {
      const int k = l + (i << 6);
      ws[OFF_XA + (row << 9) + k] = (x[i] - mu) * rstd * ag[k] + ab[k];
    }
  } else {
    // ---- c path: concat + LN (din=1024)
    const int w = b - 336;
    const float v0 = csum[(w << 9) + tid];
    const float v1 = ectx[(w << 9) + tid];
    float s = v0 + v1, ss = v0 * v0 + v1 * v1;
#pragma unroll
    for (int off = 1; off < 64; off <<= 1) {
      s += __shfl_xor(s, off); ss += __shfl_xor(ss, off);
    }
    if (l == 0) { sh[wv] = s; sh[8 + wv] = ss; }
    __syncthreads();
    float st = 0.f, sst = 0.f;
#pragma unroll
    for (int i = 0; i < 8; ++i) { st += sh[i]; sst += sh[8 + i]; }
    const float mu = st * (1.0f / 1024.0f);
    const float rstd = rsqrtf(sst * (1.0f / 1024.0f) - mu * mu + 1e-5f);
    ws[OFF_XC + (w << 10) + tid] = (v0 - mu) * rstd * cg[tid] + cb[tid];
    ws[OFF_XC + (w << 10) + 512 + tid] =
        (v1 - mu) * rstd * cg[512 + tid] + cb[512 + tid];
  }
}

// ======================== generic FC tile ===================================
// 256 threads: c = ct*128 + tid%128, rg = tid/128; RPT rows per thread.
// out[r][c] = (gelu?)( bias[c] + sum_k A[r][k] * (s?s[k]:1) * W[k][c] )
template <int RPT, bool GELU, bool HAS_S, bool SROW>
DEV void fc_tile(const float* __restrict__ A, int lda,
                 const float* __restrict__ W, const float* __restrict__ bias,
                 const float* __restrict__ s, float* __restrict__ O,
                 int K, int rt, int ct, int tid) {
  const int c = (ct << 7) + (tid & 127);
  const int rg = tid >> 7;
  const int r0 = SROW ? 0 : rt * (2 * RPT) + rg * RPT;
  float acc[RPT];
#pragma unroll
  for (int j = 0; j < RPT; ++j) acc[j] = 0.f;
#pragma unroll 4
  for (int k0 = 0; k0 < K; k0 += 4) {
    float w0 = W[(k0 + 0) * 512 + c];
    float w1 = W[(k0 + 1) * 512 + c];
    float w2 = W[(k0 + 2) * 512 + c];
    float w3 = W[(k0 + 3) * 512 + c];
    if (HAS_S) {
      w0 *= s[k0]; w1 *= s[k0 + 1]; w2 *= s[k0 + 2]; w3 *= s[k0 + 3];
    }
#pragma unroll
    for (int j = 0; j < RPT; ++j) {
      const float4 xv = *(const float4*)(A + (r0 + j) * lda + k0);
      acc[j] = fmaf(xv.w, w3, fmaf(xv.z, w2, fmaf(xv.y, w1, fmaf(xv.x, w0, acc[j]))));
    }
  }
  const float bv = bias ? bias[c] : 0.f;
#pragma unroll
  for (int j = 0; j < RPT; ++j) {
    float o = acc[j] + bv;
    if (GELU) o = gelu_fast(o);
    O[(r0 + j) * 512 + c] = o;
  }
}

// ---- FC1: layer1 (a/q/c) + Waya/Wqyq + bya/byq -----------------------------
__global__ __launch_bounds__(256) void fc1_kernel(
    float* __restrict__ ws,
    const float* __restrict__ aw1, const float* __restrict__ ab1,
    const float* __restrict__ qw1, const float* __restrict__ qb1,
    const float* __restrict__ cw1, const float* __restrict__ cb1,
    const float* __restrict__ aw2, const float* __restrict__ qw2,
    const float* __restrict__ ab2, const float* __restrict__ qb2,
    const float* __restrict__ rw1, const float* __restrict__ rg) {
  const int b = blockIdx.x, tid = threadIdx.x;
  if (b < 256) {           // a layer1: 1024 rows, 16/block
    fc_tile<8, true, false, false>(ws + OFF_XA, 512, aw1, ab1, nullptr,
                                   ws + OFF_HA, 512, b >> 2, b & 3, tid);
  } else if (b < 272) {    // q layer1: 64 rows
    const int bb = b - 256;
    fc_tile<8, true, false, false>(ws + OFF_XQ, 512, qw1, qb1, nullptr,
                                   ws + OFF_HQ, 512, bb >> 2, bb & 3, tid);
  } else if (b < 276) {    // c layer1: 16 rows, K=1024
    fc_tile<8, true, false, false>(ws + OFF_XC, 1024, cw1, cb1, nullptr,
                                   ws + OFF_HC, 1024, 0, b - 272, tid);
  } else if (b < 404) {    // Waya[k][n] = sum_j aw2[k][j]*rg[j]*rw1[j][n]
    const int bb = b - 276;
    fc_tile<8, false, true, false>(aw2, 512, rw1, nullptr, rg,
                                   ws + OFF_WAYA, 512, bb >> 2, bb & 3, tid);
  } else if (b < 532) {    // Wqyq[k][n] = sum_j qw2[k][j]*rg[512+j]*rw1hi[j][n]
    const int bb = b - 404;
    fc_tile<8, false, true, false>(qw2, 512, rw1 + 512 * 512, nullptr, rg + 512,
                                   ws + OFF_WQYQ, 512, bb >> 2, bb & 3, tid);
  } else if (b < 536) {    // bya[n] = sum_j ab2[j]*rg[j]*rw1[j][n]
    fc_tile<1, false, true, true>(ab2, 0, rw1, nullptr, rg,
                                  ws + OFF_BYA, 512, 0, b - 532, tid);
  } else {                 // byq[n] = sum_j qb2[j]*rg[512+j]*rw1hi[j][n]
    fc_tile<1, false, true, true>(qb2, 0, rw1 + 512 * 512, nullptr, rg + 512,
                                  ws + OFF_BYQ, 512, 0, b - 536, tid);
  }
}

// ---- FC2: layer2 (ahh/qh/chh) + Ya/Yq (via Waya/Wqyq) ----------------------
__global__ __launch_bounds__(256) void fc2_kernel(
    float* __restrict__ ws,
    const float* __restrict__ aw2, const float* __restrict__ ab2,
    const float* __restrict__ qw2, const float* __restrict__ qb2,
    const float* __restrict__ cw2, const float* __restrict__ cb2) {
  const int b = blockIdx.x, tid = threadIdx.x;
  if (b < 256) {           // ahh = ha @ aw2 + ab2
    fc_tile<8, false, false, false>(ws + OFF_HA, 512, aw2, ab2, nullptr,
                                    ws + OFF_AHH, 512, b >> 2, b & 3, tid);
  } else if (b < 512) {    // Ya = ha @ Waya + bya
    const int bb = b - 256;
    fc_tile<8, false, false, false>(ws + OFF_HA, 512, ws + OFF_WAYA,
                                    ws + OFF_BYA, nullptr, ws + OFF_YA, 512,
                                    bb >> 2, bb & 3, tid);
  } else if (b < 528) {    // qh = hq @ qw2 + qb2
    const int bb = b - 512;
    fc_tile<8, false, false, false>(ws + OFF_HQ, 512, qw2, qb2, nullptr,
                                    ws + OFF_QH, 512, bb >> 2, bb & 3, tid);
  } else if (b < 544) {    // Yq = hq @ Wqyq + byq
    const int bb = b - 528;
    fc_tile<8, false, false, false>(ws + OFF_HQ, 512, ws + OFF_WQYQ,
                                    ws + OFF_BYQ, nullptr, ws + OFF_YQ, 512,
                                    bb >> 2, bb & 3, tid);
  } else {                 // chh = hc @ cw2 + cb2
    fc_tile<8, false, false, false>(ws + OFF_HC, 512, cw2, cb2, nullptr,
                                    ws + OFF_CHH, 512, 0, b - 544, tid);
  }
}

// ---------------------------- main fused kernel -----------------------------
// 1 block per (q,w), 1024 threads = 16 waves, wave -> 64 rows x 32 cols.
// 4 K-chunks of 256, double-buffered 32KB LDS; T14 pipeline per chunk:
//   issue next-chunk global loads -> MFMA current -> compute/ds_write next.
__global__ __launch_bounds__(1024, 4) void main_kernel(
    const float* __restrict__ AH, const float* __restrict__ QH,
    const float* __restrict__ CH, const unsigned short* __restrict__ WT2,
    const float* __restrict__ Ya, const float* __restrict__ Yq,
    const float* __restrict__ S1, const float* __restrict__ B1,
    const float* __restrict__ rb1, const float* __restrict__ rw2,
    const float* __restrict__ rb2, const float* __restrict__ cmass,
    float* __restrict__ out) {
  extern __shared__ char smem_raw[];
  float* qs = (float*)smem_raw;          // 512
  float* cs = qs + 512;                  // 512
  float* s1_s = cs + 512;                // 64
  float* s2_s = s1_s + 64;               // 64
  float* rel_s = s2_s + 64;              // 64
  float* misc = rel_s + 64;              // 2 (+pad to 5120 B)
  uint4* apv = (uint4*)(smem_raw + 5120);  // 2 x 32KB: [buf][ksl(8)][fr(4)][l(64)]

  const int tid = threadIdx.x;
  const int l = tid & 63;
  const int wv = tid >> 6;               // 0..15
  const int q = blockIdx.x >> 4;
  const int w = blockIdx.x & 15;

  if (tid < 512) qs[tid] = QH[(q << 9) + tid];
  else cs[tid - 512] = CH[(w << 9) + (tid - 512)];
  if (tid < 64) { s1_s[tid] = 0.f; s2_s[tid] = 0.f; rel_s[tid] = 0.f; }
  __syncthreads();

  const int rloc = ((wv & 3) << 4) + (l & 15);
  const float* arow = AH + (((w << 6) + rloc) << 9);
  const int kh = (l >> 4) << 3;          // 0,8,16,24
  const int par = wv >> 2;               // 0..3 ; ksl = par + 4*i, i in {0,1}
  float s1a = 0.f, s2a = 0.f;
  float4 pav[2][2];

#define BUILD_LOAD(C) do { \
    _Pragma("unroll") for (int i_ = 0; i_ < 2; ++i_) { \
      const int ks_ = ((C) << 3) + par + (i_ << 2); \
      const int ka_ = ((ks_ << 5) + kh) & 511; \
      pav[i_][0] = *(const float4*)(arow + ka_); \
      pav[i_][1] = *(const float4*)(arow + ka_ + 4); \
    } } while (0)

#define BUILD_STORE(C, B) do { \
    _Pragma("unroll") for (int i_ = 0; i_ < 2; ++i_) { \
      const int ksl_ = par + (i_ << 2); \
      const int ka_ = (((((C) << 3) + ksl_) << 5) + kh) & 511; \
      const float av_[8] = {pav[i_][0].x, pav[i_][0].y, pav[i_][0].z, pav[i_][0].w, \
                            pav[i_][1].x, pav[i_][1].y, pav[i_][1].z, pav[i_][1].w}; \
      const float4 q0_ = *(const float4*)(qs + ka_); \
      const float4 q1_ = *(const float4*)(qs + ka_ + 4); \
      const float qv_[8] = {q0_.x, q0_.y, q0_.z, q0_.w, q1_.x, q1_.y, q1_.z, q1_.w}; \
      float vv_[8]; \
      if ((C) < 2) { \
        _Pragma("unroll") for (int j_ = 0; j_ < 8; ++j_) { \
          const float aq_ = av_[j_] * qv_[j_]; \
          vv_[j_] = aq_; \
          s1a += av_[j_] + aq_; \
          s2a += av_[j_] * av_[j_] + aq_ * aq_; \
        } \
      } else { \
        const float4 c0_ = *(const float4*)(cs + ka_); \
        const float4 c1_ = *(const float4*)(cs + ka_ + 4); \
        const float cv_[8] = {c0_.x, c0_.y, c0_.z, c0_.w, c1_.x, c1_.y, c1_.z, c1_.w}; \
        _Pragma("unroll") for (int j_ = 0; j_ < 8; ++j_) { \
          const float dd_ = fabsf(av_[j_] - qv_[j_]) + cv_[j_]; \
          vv_[j_] = dd_; \
          s1a += dd_; \
          s2a += dd_ * dd_; \
        } \
      } \
      union { unsigned short us[8]; uint4 u4; } pk_; \
      _Pragma("unroll") for (int j_ = 0; j_ < 8; ++j_) pk_.us[j_] = f2bf(vv_[j_]); \
      apv[((B) << 11) + (ksl_ << 8) + ((wv & 3) << 6) + l] = pk_.u4; \
    } } while (0)

  // ---- prologue: build chunk 0 into buf 0 + q-segment stats
  BUILD_LOAD(0);
  BUILD_STORE(0, 0);
  if (wv == 0) {
    float sq = 0.f, sqq = 0.f;
#pragma unroll
    for (int it = 0; it < 8; ++it) {
      const float vq = qs[l + (it << 6)];
      sq += vq; sqq += vq * vq;
    }
#pragma unroll
    for (int off = 1; off < 64; off <<= 1) {
      sq += __shfl_xor(sq, off); sqq += __shfl_xor(sqq, off);
    }
    if (l == 0) { misc[0] = sq; misc[1] = sqq; }
  }
  __syncthreads();

  // ---- pipelined chunk loop: wave wv owns cols [wv*32, wv*32+32) ----------
  f32x4 acc[4][2] = {};
  const int ncb = (wv << 5) + (l & 15);
#pragma unroll
  for (int c = 0; c < 4; ++c) {
    if (c < 3) BUILD_LOAD(c + 1);          // global loads in flight over MFMA
    const uint4* cbuf = apv + ((c & 1) << 11);
#pragma unroll
    for (int ksl = 0; ksl < 8; ++ksl) {
      const int ks = (c << 3) + ksl;
      bf16x8 bfr[2];
#pragma unroll
      for (int cf = 0; cf < 2; ++cf)
        bfr[cf] = __builtin_bit_cast(bf16x8,
            *(const uint4*)(WT2 + (ks << 14) + ((ncb + (cf << 4)) << 5) + kh));
#pragma unroll
      for (int fr = 0; fr < 4; ++fr) {
        const bf16x8 afr =
            __builtin_bit_cast(bf16x8, cbuf[(ksl << 8) + (fr << 6) + l]);
#pragma unroll
        for (int cf = 0; cf < 2; ++cf)
          acc[fr][cf] = __builtin_amdgcn_mfma_f32_16x16x32_bf16(
              afr, bfr[cf], acc[fr][cf], 0, 0, 0);
      }
    }
    if (c == 0) BUILD_STORE(1, 1);
    if (c == 1) BUILD_STORE(2, 0);
    if (c == 2) {
      BUILD_STORE(3, 1);
      // all build contributions done -> fold stats into per-row LDS totals
      s1a += __shfl_xor(s1a, 16); s1a += __shfl_xor(s1a, 32);
      s2a += __shfl_xor(s2a, 16); s2a += __shfl_xor(s2a, 32);
      if ((l >> 4) == 0) {
        atomicAdd(&s1_s[rloc], s1a);
        atomicAdd(&s2_s[rloc], s2a);
      }
    }
    __syncthreads();
  }
#undef BUILD_LOAD
#undef BUILD_STORE

  // ---- epilogue: LN-fold + gelu + dot(rw2) -> per-row relevance -----------
  {
    const float sqt = misc[0], sqqt = misc[1];
    float yqv[2], s1c[2], b1c[2], w2c[2];
#pragma unroll
    for (int cf = 0; cf < 2; ++cf) {
      const int n = ncb + (cf << 4);
      yqv[cf] = Yq[(q << 9) + n];
      s1c[cf] = S1[n];
      b1c[cf] = B1[n] + rb1[n];
      w2c[cf] = rw2[n];
    }
    const float* yab = Ya + (w << 15) + ncb;
    const int rsub = (l >> 4) << 2;
#pragma unroll
    for (int fr = 0; fr < 4; ++fr) {
#pragma unroll
      for (int j = 0; j < 4; ++j) {
        const int r = (fr << 4) + rsub + j;
        const float s1r = s1_s[r] + sqt;
        const float s2r = s2_s[r] + sqqt;
        const float mu = s1r * (1.0f / 2048.0f);
        const float rs = rsqrtf(s2r * (1.0f / 2048.0f) - mu * mu + 1e-5f);
        float rp = 0.f;
#pragma unroll
        for (int cf = 0; cf < 2; ++cf) {
          const float ya = yab[(r << 9) + (cf << 4)];
          const float hp = rs * (acc[fr][cf][j] + ya + yqv[cf] - mu * s1c[cf]) + b1c[cf];
          rp += gelu_fast(hp) * w2c[cf];
        }
        rp += __shfl_xor(rp, 1); rp += __shfl_xor(rp, 2);
        rp += __shfl_xor(rp, 4); rp += __shfl_xor(rp, 8);
        if ((l & 15) == 0) atomicAdd(&rel_s[r], rp);
      }
    }
  }
  __syncthreads();

  // ---- softmax over atoms + entropy (wave 0)
  if (tid < 64) {
    const float relv = rel_s[tid] + rb2[0];
    const float x = logf(fmaxf(cmass[(w << 6) + tid], 1e-8f)) + relv;
    float m = x;
#pragma unroll
    for (int off = 1; off < 64; off <<= 1) m = fmaxf(m, __shfl_xor(m, off));
    const float p = expf(x - m);
    float s = p;
#pragma unroll
    for (int off = 1; off < 64; off <<= 1) s += __shfl_xor(s, off);
    float mix = p / fmaxf(s, 1e-8f);
    float s2 = mix;
#pragma unroll
    for (int off = 1; off < 64; off <<= 1) s2 += __shfl_xor(s2, off);
    mix = mix / fmaxf(s2, 1e-8f);
    const float et = -mix * logf(fmaxf(mix, 1e-8f));
    float ent = et;
#pragma unroll
    for (int off = 1; off < 64; off <<= 1) ent += __shfl_xor(ent, off);
    out[(blockIdx.x << 6) + tid] = mix;                 // mixed[q][w][a]
    if (tid == 0) out[65536 + blockIdx.x] = ent;        // entropy[q][w]
  }
}

// ---------------------------------------------------------------------------
extern "C" void kernel_launch(void* const* d_in, const int* in_sizes, int n_in,
                              void* d_out, int out_size, void* d_ws, size_t ws_size,
                              hipStream_t stream) {
  (void)in_sizes; (void)n_in; (void)out_size; (void)ws_size;
  const float* q_atoms = (const float*)d_in[0];
  const float* q_mass  = (const float*)d_in[1];
  const float* c_atoms = (const float*)d_in[2];
  const float* c_mass  = (const float*)d_in[3];
  const float* c_sum   = (const float*)d_in[4];
  const float* e_ctx   = (const float*)d_in[5];
  const float* qg  = (const float*)d_in[6];  const float* qb  = (const float*)d_in[7];
  const float* qw1 = (const float*)d_in[8];  const float* qb1 = (const float*)d_in[9];
  const float* qw2 = (const float*)d_in[10]; const float* qb2 = (const float*)d_in[11];
  const float* ag  = (const float*)d_in[12]; const float* ab  = (const float*)d_in[13];
  const float* aw1 = (const float*)d_in[14]; const float* ab1 = (const float*)d_in[15];
  const float* aw2 = (const float*)d_in[16]; const float* ab2 = (const float*)d_in[17];
  const float* cg  = (const float*)d_in[18]; const float* cb  = (const float*)d_in[19];
  const float* cw1 = (const float*)d_in[20]; const float* cb1 = (const float*)d_in[21];
  const float* cw2 = (const float*)d_in[22]; const float* cb2 = (const float*)d_in[23];
  const float* rg  = (const float*)d_in[24]; const float* rb  = (const float*)d_in[25];
  const float* rw1 = (const float*)d_in[26]; const float* rb1 = (const float*)d_in[27];
  const float* rw2 = (const float*)d_in[28]; const float* rb2 = (const float*)d_in[29];

  float* ws = (float*)d_ws;
  float* out = (float*)d_out;

  hipMemsetAsync(ws + OFF_S1, 0, 1024 * sizeof(float), stream);  // S1+B1
  pre0_kernel<<<352, 512, 0, stream>>>(q_atoms, q_mass, c_atoms, c_sum, e_ctx,
                                       qg, qb, ag, ab, cg, cb, rw1, rg, rb, ws);
  fc1_kernel<<<540, 256, 0, stream>>>(ws, aw1, ab1, qw1, qb1, cw1, cb1,
                                      aw2, qw2, ab2, qb2, rw1, rg);
  fc2_kernel<<<548, 256, 0, stream>>>(ws, aw2, ab2, qw2, qb2, cw2, cb2);

  static const size_t MAIN_SMEM = 5120 + 65536;  // 70656 B
  hipFuncSetAttribute((const void*)main_kernel,
                      hipFuncAttributeMaxDynamicSharedMemorySize, (int)MAIN_SMEM);
  main_kernel<<<1024, 1024, MAIN_SMEM, stream>>>(
      ws + OFF_AHH, ws + OFF_QH, ws + OFF_CHH,
      (const unsigned short*)(ws + OFF_WT), ws + OFF_YA, ws + OFF_YQ,
      ws + OFF_S1, ws + OFF_B1, rb1, rw2, rb2, c_mass, out);
}

// Round 6
// 249.377 us; speedup vs baseline: 2.1793x; 1.8231x over previous
//
#include <hip/hip_runtime.h>

// ---------------------------------------------------------------------------
// QueryConditionedTransportScorerV3 on MI355X (gfx950)
// Q=64 W=16 A=64 D=H=512.
//   fused@rw1 = Ya[w,a] + Yq[q] + [a*q ; |a-q|+c] @ (rg*rw1)[1024:2048] (MFMA)
//   h = rstd*(sum - mu*S1) + (rb1 + rb@rw1); gelu; @rw2; softmax+entropy fused
// Round 6: pre-path MFMA-ified — prep emits bf16 A-mats + transposed bf16
//   weights; 3 small MFMA GEMM phases (L1+gelu, L2+scaled-copy, Ya/Yq)
//   replace the latency-bound f32 fc kernels. Main kernel = round-5.
// ---------------------------------------------------------------------------

#define DEV static __device__ __forceinline__

typedef __attribute__((ext_vector_type(8))) __bf16 bf16x8;
typedef __attribute__((ext_vector_type(4))) float f32x4;
typedef unsigned short ushort_t;

DEV ushort_t f2bf(float f) {
  unsigned u = __builtin_bit_cast(unsigned, f);
  u = (u + 0x7fffu + ((u >> 16) & 1u)) >> 16;
  return (ushort_t)u;
}

// branch-free erf (Abramowitz-Stegun 7.1.26, |err| <= 1.5e-7)
DEV float gelu_fast(float x) {
  const float y = x * 0.70710678118654752f;
  const float z = fabsf(y);
  const float t = __fdividef(1.0f, 1.0f + 0.3275911f * z);
  float p = 1.061405429f;
  p = p * t - 1.453152027f;
  p = p * t + 1.421413741f;
  p = p * t - 0.284496736f;
  p = p * t + 0.254829592f;
  const float e = 1.0f - p * t * __expf(-z * z);
  const float erfv = copysignf(e, y);
  return 0.5f * x * (1.0f + erfv);
}

// ---- ws layout (float offsets) --------------------------------------------
#define OFF_XQB    0          // bf16 64x512    (aliased by QHS after P1)
#define OFF_XAB    16384      // bf16 1024x512  (aliased by AHHS after P1)
#define OFF_XCB    278528     // bf16 16x1024   (aliased by CHH f32 after P1)
#define OFF_HAB    286720     // bf16 1024x512
#define OFF_HQB    548864     // bf16 64x512
#define OFF_HCB    565248     // bf16 16x512
#define OFF_AHH    569344     // f32 1024x512
#define OFF_QH     1093632    // f32 64x512
#define OFF_S1     1126400    // f32 512
#define OFF_B1     1126912    // f32 512
#define OFF_WT2    1127424    // bf16 k-tiled hi rw1 (rg-scaled), 524288 el
#define OFF_RW1LOT 1389568    // bf16 [512n][512k] rw1[0:512]
#define OFF_RW1MIT 1520640    // bf16 [512n][512k] rw1[512:1024]
#define OFF_AW1T   1651712    // bf16 [512][512]   ┐
#define OFF_QW1T   1782784    // bf16 [512][512]   ├ dead after P1 -> YA
#define OFF_CW1T   1913856    // bf16 [512][1024]  ┘
#define OFF_AW2T   2176000    // bf16 [512][512]   ┐ dead after P2 -> YQ
#define OFF_QW2T   2307072    // bf16 [512][512]   ┘
#define OFF_CW2T   2438144    // bf16 [512][512]   (end: 2569216 fl)
#define OFF_YA     OFF_AW1T   // f32 1024x512
#define OFF_YQ     OFF_AW2T   // f32 64x512
#define OFF_CHH    OFF_XCB    // f32 16x512
#define OFF_AHHS   OFF_XAB    // bf16 1024x512 (ahh*rg_lo)
#define OFF_QHS    OFF_XQB    // bf16 64x512   (qh*rg_mid)

// WT2 k-tiled layout: element (n, k2) at (k2>>5)*16384 + n*32 + (k2&31).

// ======================== P0: wide prep kernel ==============================
DEV void transpose_tile(const float* __restrict__ src, int koff, int kt, int ct,
                        ushort_t* __restrict__ dst, int ldk, float* sh, int tid) {
  float (*t)[65] = (float(*)[65])sh;
  for (int idx = tid; idx < 4096; idx += 512) {
    const int r = idx >> 6, c = idx & 63;
    t[r][c] = src[(koff + kt + r) * 512 + ct + c];
  }
  __syncthreads();
  for (int idx = tid; idx < 4096; idx += 512) {
    const int c = idx >> 6, r = idx & 63;
    dst[(ct + c) * ldk + kt + r] = f2bf(t[r][c]);
  }
}

// roles: [0,128) WT2 | [128,192) rw1loT | [192,256) rw1midT | [256,320) aw1T
// [320,384) qw1T | [384,512) cw1T | [512,576) aw2T | [576,640) qw2T
// [640,704) cw2T | [704,720) S1/B1 | [720,784) q pool+LN | [784,912) a LN
// [912,928) c concat+LN
__global__ __launch_bounds__(512) void pre0_kernel(
    const float* __restrict__ qa, const float* __restrict__ qm,
    const float* __restrict__ ca, const float* __restrict__ csum,
    const float* __restrict__ ectx,
    const float* __restrict__ qg, const float* __restrict__ qb,
    const float* __restrict__ ag, const float* __restrict__ ab,
    const float* __restrict__ cg, const float* __restrict__ cb,
    const float* __restrict__ rw1, const float* __restrict__ rg,
    const float* __restrict__ rb,
    const float* __restrict__ aw1, const float* __restrict__ qw1,
    const float* __restrict__ cw1, const float* __restrict__ aw2,
    const float* __restrict__ qw2, const float* __restrict__ cw2,
    float* __restrict__ ws) {
  __shared__ float sh[4160];
  const int b = blockIdx.x, tid = threadIdx.x, l = tid & 63, wv = tid >> 6;

  if (b < 128) {
    // ---- WT2[(k2>>5)][n][k2&31] = rg[1024+k2] * rw1[1024+k2][n]
    ushort_t* WT = (ushort_t*)(ws + OFF_WT2);
    float (*t)[65] = (float(*)[65])sh;
    const int kt = (b >> 3) << 6;
    const int ct = (b & 7) << 6;
    for (int idx = tid; idx < 4096; idx += 512) {
      const int r = idx >> 6, c = idx & 63;
      t[r][c] = rg[1024 + kt + r] * rw1[(1024 + kt + r) * 512 + ct + c];
    }
    __syncthreads();
    for (int idx = tid; idx < 4096; idx += 512) {
      const int c = idx >> 6, r = idx & 63;
      const int n = ct + c, k2 = kt + r;
      WT[((k2 >> 5) << 14) + (n << 5) + (k2 & 31)] = f2bf(t[r][c]);
    }
  } else if (b < 192) {
    const int bb = b - 128;
    transpose_tile(rw1, 0, (bb >> 3) << 6, (bb & 7) << 6,
                   (ushort_t*)(ws + OFF_RW1LOT), 512, sh, tid);
  } else if (b < 256) {
    const int bb = b - 192;
    transpose_tile(rw1, 512, (bb >> 3) << 6, (bb & 7) << 6,
                   (ushort_t*)(ws + OFF_RW1MIT), 512, sh, tid);
  } else if (b < 320) {
    const int bb = b - 256;
    transpose_tile(aw1, 0, (bb >> 3) << 6, (bb & 7) << 6,
                   (ushort_t*)(ws + OFF_AW1T), 512, sh, tid);
  } else if (b < 384) {
    const int bb = b - 320;
    transpose_tile(qw1, 0, (bb >> 3) << 6, (bb & 7) << 6,
                   (ushort_t*)(ws + OFF_QW1T), 512, sh, tid);
  } else if (b < 512) {
    const int bb = b - 384;
    transpose_tile(cw1, 0, (bb >> 3) << 6, (bb & 7) << 6,
                   (ushort_t*)(ws + OFF_CW1T), 1024, sh, tid);
  } else if (b < 576) {
    const int bb = b - 512;
    transpose_tile(aw2, 0, (bb >> 3) << 6, (bb & 7) << 6,
                   (ushort_t*)(ws + OFF_AW2T), 512, sh, tid);
  } else if (b < 640) {
    const int bb = b - 576;
    transpose_tile(qw2, 0, (bb >> 3) << 6, (bb & 7) << 6,
                   (ushort_t*)(ws + OFF_QW2T), 512, sh, tid);
  } else if (b < 704) {
    const int bb = b - 640;
    transpose_tile(cw2, 0, (bb >> 3) << 6, (bb & 7) << 6,
                   (ushort_t*)(ws + OFF_CW2T), 512, sh, tid);
  } else if (b < 720) {
    // ---- S1[n] += sum rg[k]*rw1[k][n]; B1[n] += sum rb[k]*rw1[k][n]
    const int kc = (b - 704) << 7;
    float s0 = 0.f, s1 = 0.f, b0 = 0.f, b1v = 0.f;
    for (int k = kc; k < kc + 128; k += 2) {
      const float wa = rw1[(k << 9) + tid];
      const float wb = rw1[((k + 1) << 9) + tid];
      s0 += rg[k] * wa; b0 += rb[k] * wa;
      s1 += rg[k + 1] * wb; b1v += rb[k + 1] * wb;
    }
    atomicAdd(ws + OFF_S1 + tid, s0 + s1);
    atomicAdd(ws + OFF_B1 + tid, b0 + b1v);
  } else if (b < 784) {
    // ---- q path: masses -> pool -> LN -> XQb (bf16)
    const int q = b - 720;
    if (wv == 0) {
      float m = fmaxf(qm[(q << 6) + l], 0.f);
      sh[l] = m;
      float s = m;
#pragma unroll
      for (int off = 1; off < 64; off <<= 1) s += __shfl_xor(s, off);
      if (l == 0) sh[64] = 1.0f / fmaxf(s, 1e-8f);
    }
    __syncthreads();
    const float sinv = sh[64];
    const float* qaq = qa + (q << 15) + tid;
    float v0 = 0.f, v1 = 0.f, v2 = 0.f, v3 = 0.f;
#pragma unroll 4
    for (int a = 0; a < 64; a += 4) {
      v0 += sh[a] * qaq[a << 9];
      v1 += sh[a + 1] * qaq[(a + 1) << 9];
      v2 += sh[a + 2] * qaq[(a + 2) << 9];
      v3 += sh[a + 3] * qaq[(a + 3) << 9];
    }
    const float v = (v0 + v1 + v2 + v3) * sinv;
    float s = v, ss = v * v;
#pragma unroll
    for (int off = 1; off < 64; off <<= 1) {
      s += __shfl_xor(s, off); ss += __shfl_xor(ss, off);
    }
    if (l == 0) { sh[128 + wv] = s; sh[136 + wv] = ss; }
    __syncthreads();
    float st = 0.f, sst = 0.f;
#pragma unroll
    for (int i = 0; i < 8; ++i) { st += sh[128 + i]; sst += sh[136 + i]; }
    const float mu = st * (1.0f / 512.0f);
    const float rstd = rsqrtf(sst * (1.0f / 512.0f) - mu * mu + 1e-5f);
    ((ushort_t*)(ws + OFF_XQB))[(q << 9) + tid] =
        f2bf((v - mu) * rstd * qg[tid] + qb[tid]);
  } else if (b < 912) {
    // ---- a path LN: wave per row -> XAb (bf16)
    const int row = ((b - 784) << 3) + wv;
    const float* crow = ca + (row << 9);
    float x[8];
    float s = 0.f, ss = 0.f;
#pragma unroll
    for (int i = 0; i < 8; ++i) {
      x[i] = crow[l + (i << 6)];
      s += x[i]; ss += x[i] * x[i];
    }
#pragma unroll
    for (int off = 1; off < 64; off <<= 1) {
      s += __shfl_xor(s, off); ss += __shfl_xor(ss, off);
    }
    const float mu = s * (1.0f / 512.0f);
    const float rstd = rsqrtf(ss * (1.0f / 512.0f) - mu * mu + 1e-5f);
    ushort_t* xab = (ushort_t*)(ws + OFF_XAB);
#pragma unroll
    for (int i = 0; i < 8; ++i) {
      const int k = l + (i << 6);
      xab[(row << 9) + k] = f2bf((x[i] - mu) * rstd * ag[k] + ab[k]);
    }
  } else {
    // ---- c path: concat + LN (din=1024) -> XCb (bf16)
    const int w = b - 912;
    const float v0 = csum[(w << 9) + tid];
    const float v1 = ectx[(w << 9) + tid];
    float s = v0 + v1, ss = v0 * v0 + v1 * v1;
#pragma unroll
    for (int off = 1; off < 64; off <<= 1) {
      s += __shfl_xor(s, off); ss += __shfl_xor(ss, off);
    }
    if (l == 0) { sh[wv] = s; sh[8 + wv] = ss; }
    __syncthreads();
    float st = 0.f, sst = 0.f;
#pragma unroll
    for (int i = 0; i < 8; ++i) { st += sh[i]; sst += sh[8 + i]; }
    const float mu = st * (1.0f / 1024.0f);
    const float rstd = rsqrtf(sst * (1.0f / 1024.0f) - mu * mu + 1e-5f);
    ushort_t* xcb = (ushort_t*)(ws + OFF_XCB);
    xcb[(w << 10) + tid] = f2bf((v0 - mu) * rstd * cg[tid] + cb[tid]);
    xcb[(w << 10) + 512 + tid] =
        f2bf((v1 - mu) * rstd * cg[512 + tid] + cb[512 + tid]);
  }
}

// ======================== MFMA GEMM phases ==================================
// Block = 4 waves; wave wv computes a 64x64 tile at (rb, cb + wv*64).
// A bf16 row-major [M][K]; BT bf16 n-major [512][K] (same frag layout as main).
// PHASE 1: H = gelu(X@W1 + b1) -> bf16.  PHASE 2: L2 = H@W2 + b2 -> f32
// (+ scaled bf16 copy for P3).  PHASE 3: Y = S @ rw1T -> f32 (no bias).
template <int PHASE>
__global__ __launch_bounds__(256) void gemm_kernel(
    float* __restrict__ ws, const float* __restrict__ ba,
    const float* __restrict__ bq, const float* __restrict__ bc,
    const float* __restrict__ rg) {
  const int b = blockIdx.x, tid = threadIdx.x;
  const int l = tid & 63, wv = tid >> 6;

  const ushort_t* A; const ushort_t* BT;
  float* outF = nullptr; ushort_t* outB = nullptr; ushort_t* outS = nullptr;
  const float* bias = nullptr; const float* scl = nullptr;
  int M, K, rb, cb;

  if (PHASE == 1) {
    if (b < 32) {
      A = (const ushort_t*)(ws + OFF_XAB); BT = (const ushort_t*)(ws + OFF_AW1T);
      M = 1024; K = 512; rb = (b >> 1) << 6; cb = (b & 1) << 8;
      outB = (ushort_t*)(ws + OFF_HAB); bias = ba;
    } else if (b < 34) {
      A = (const ushort_t*)(ws + OFF_XQB); BT = (const ushort_t*)(ws + OFF_QW1T);
      M = 64; K = 512; rb = 0; cb = (b - 32) << 8;
      outB = (ushort_t*)(ws + OFF_HQB); bias = bq;
    } else {
      A = (const ushort_t*)(ws + OFF_XCB); BT = (const ushort_t*)(ws + OFF_CW1T);
      M = 16; K = 1024; rb = 0; cb = (b - 34) << 8;
      outB = (ushort_t*)(ws + OFF_HCB); bias = bc;
    }
  } else if (PHASE == 2) {
    if (b < 32) {
      A = (const ushort_t*)(ws + OFF_HAB); BT = (const ushort_t*)(ws + OFF_AW2T);
      M = 1024; K = 512; rb = (b >> 1) << 6; cb = (b & 1) << 8;
      outF = ws + OFF_AHH; outS = (ushort_t*)(ws + OFF_AHHS); bias = ba; scl = rg;
    } else if (b < 34) {
      A = (const ushort_t*)(ws + OFF_HQB); BT = (const ushort_t*)(ws + OFF_QW2T);
      M = 64; K = 512; rb = 0; cb = (b - 32) << 8;
      outF = ws + OFF_QH; outS = (ushort_t*)(ws + OFF_QHS); bias = bq; scl = rg + 512;
    } else {
      A = (const ushort_t*)(ws + OFF_HCB); BT = (const ushort_t*)(ws + OFF_CW2T);
      M = 16; K = 512; rb = 0; cb = (b - 34) << 8;
      outF = ws + OFF_CHH; bias = bc;
    }
  } else {
    if (b < 32) {
      A = (const ushort_t*)(ws + OFF_AHHS); BT = (const ushort_t*)(ws + OFF_RW1LOT);
      M = 1024; K = 512; rb = (b >> 1) << 6; cb = (b & 1) << 8;
      outF = ws + OFF_YA;
    } else {
      A = (const ushort_t*)(ws + OFF_QHS); BT = (const ushort_t*)(ws + OFF_RW1MIT);
      M = 64; K = 512; rb = 0; cb = (b - 32) << 8;
      outF = ws + OFF_YQ;
    }
  }

  const int colw = cb + (wv << 6);
  const int kh = (l >> 4) << 3;
  const ushort_t* ap[4];
  const ushort_t* bp[4];
#pragma unroll
  for (int fr = 0; fr < 4; ++fr) {
    int r = rb + (fr << 4) + (l & 15);
    if (r > M - 1) r = M - 1;          // row clamp for small-M tiles
    ap[fr] = A + r * K + kh;
  }
#pragma unroll
  for (int cf = 0; cf < 4; ++cf) {
    const int ccol = colw + (cf << 4) + (l & 15);
    bp[cf] = BT + ccol * K + kh;
  }

  f32x4 acc[4][4] = {};
  const int nst = K >> 5;
#pragma unroll 4
  for (int ks = 0; ks < nst; ++ks) {
    bf16x8 afr[4], bfr[4];
#pragma unroll
    for (int fr = 0; fr < 4; ++fr)
      afr[fr] = __builtin_bit_cast(bf16x8, *(const uint4*)(ap[fr] + (ks << 5)));
#pragma unroll
    for (int cf = 0; cf < 4; ++cf)
      bfr[cf] = __builtin_bit_cast(bf16x8, *(const uint4*)(bp[cf] + (ks << 5)));
#pragma unroll
    for (int fr = 0; fr < 4; ++fr)
#pragma unroll
      for (int cf = 0; cf < 4; ++cf)
        acc[fr][cf] = __builtin_amdgcn_mfma_f32_16x16x32_bf16(
            afr[fr], bfr[cf], acc[fr][cf], 0, 0, 0);
  }

  // epilogue (C layout: col = l&15 (+16cf), row = (l>>4)*4 + j (+16fr))
  const int rsub = (l >> 4) << 2, cl = l & 15;
#pragma unroll
  for (int fr = 0; fr < 4; ++fr) {
#pragma unroll
    for (int cf = 0; cf < 4; ++cf) {
      const int col = colw + (cf << 4) + cl;
#pragma unroll
      for (int j = 0; j < 4; ++j) {
        const int row = rb + (fr << 4) + rsub + j;
        if (row < M) {
          float v = acc[fr][cf][j];
          if (PHASE == 1) {
            outB[(row << 9) + col] = f2bf(gelu_fast(v + bias[col]));
          } else if (PHASE == 2) {
            v += bias[col];
            outF[(row << 9) + col] = v;
            if (outS) outS[(row << 9) + col] = f2bf(v * scl[col]);
          } else {
            outF[(row << 9) + col] = v;
          }
        }
      }
    }
  }
}

// ---------------------------- main fused kernel -----------------------------
// (round-5 version, unchanged)
__global__ __launch_bounds__(1024, 4) void main_kernel(
    const float* __restrict__ AH, const float* __restrict__ QH,
    const float* __restrict__ CH, const ushort_t* __restrict__ WT2,
    const float* __restrict__ Ya, const float* __restrict__ Yq,
    const float* __restrict__ S1, const float* __restrict__ B1,
    const float* __restrict__ rb1, const float* __restrict__ rw2,
    const float* __restrict__ rb2, const float* __restrict__ cmass,
    float* __restrict__ out) {
  extern __shared__ char smem_raw[];
  float* qs = (float*)smem_raw;          // 512
  float* cs = qs + 512;                  // 512
  float* s1_s = cs + 512;                // 64
  float* s2_s = s1_s + 64;               // 64
  float* rel_s = s2_s + 64;              // 64
  float* misc = rel_s + 64;              // 2 (+pad to 5120 B)
  uint4* apv = (uint4*)(smem_raw + 5120);  // 2 x 32KB

  const int tid = threadIdx.x;
  const int l = tid & 63;
  const int wv = tid >> 6;               // 0..15
  const int q = blockIdx.x >> 4;
  const int w = blockIdx.x & 15;

  if (tid < 512) qs[tid] = QH[(q << 9) + tid];
  else cs[tid - 512] = CH[(w << 9) + (tid - 512)];
  if (tid < 64) { s1_s[tid] = 0.f; s2_s[tid] = 0.f; rel_s[tid] = 0.f; }
  __syncthreads();

  const int rloc = ((wv & 3) << 4) + (l & 15);
  const float* arow = AH + (((w << 6) + rloc) << 9);
  const int kh = (l >> 4) << 3;          // 0,8,16,24
  const int par = wv >> 2;               // 0..3
  float s1a = 0.f, s2a = 0.f;
  float4 pav[2][2];

#define BUILD_LOAD(C) do { \
    _Pragma("unroll") for (int i_ = 0; i_ < 2; ++i_) { \
      const int ks_ = ((C) << 3) + par + (i_ << 2); \
      const int ka_ = ((ks_ << 5) + kh) & 511; \
      pav[i_][0] = *(const float4*)(arow + ka_); \
      pav[i_][1] = *(const float4*)(arow + ka_ + 4); \
    } } while (0)

#define BUILD_STORE(C, B) do { \
    _Pragma("unroll") for (int i_ = 0; i_ < 2; ++i_) { \
      const int ksl_ = par + (i_ << 2); \
      const int ka_ = (((((C) << 3) + ksl_) << 5) + kh) & 511; \
      const float av_[8] = {pav[i_][0].x, pav[i_][0].y, pav[i_][0].z, pav[i_][0].w, \
                            pav[i_][1].x, pav[i_][1].y, pav[i_][1].z, pav[i_][1].w}; \
      const float4 q0_ = *(const float4*)(qs + ka_); \
      const float4 q1_ = *(const float4*)(qs + ka_ + 4); \
      const float qv_[8] = {q0_.x, q0_.y, q0_.z, q0_.w, q1_.x, q1_.y, q1_.z, q1_.w}; \
      float vv_[8]; \
      if ((C) < 2) { \
        _Pragma("unroll") for (int j_ = 0; j_ < 8; ++j_) { \
          const float aq_ = av_[j_] * qv_[j_]; \
          vv_[j_] = aq_; \
          s1a += av_[j_] + aq_; \
          s2a += av_[j_] * av_[j_] + aq_ * aq_; \
        } \
      } else { \
        const float4 c0_ = *(const float4*)(cs + ka_); \
        const float4 c1_ = *(const float4*)(cs + ka_ + 4); \
        const float cv_[8] = {c0_.x, c0_.y, c0_.z, c0_.w, c1_.x, c1_.y, c1_.z, c1_.w}; \
        _Pragma("unroll") for (int j_ = 0; j_ < 8; ++j_) { \
          const float dd_ = fabsf(av_[j_] - qv_[j_]) + cv_[j_]; \
          vv_[j_] = dd_; \
          s1a += dd_; \
          s2a += dd_ * dd_; \
        } \
      } \
      union { ushort_t us[8]; uint4 u4; } pk_; \
      _Pragma("unroll") for (int j_ = 0; j_ < 8; ++j_) pk_.us[j_] = f2bf(vv_[j_]); \
      apv[((B) << 11) + (ksl_ << 8) + ((wv & 3) << 6) + l] = pk_.u4; \
    } } while (0)

  // ---- prologue: build chunk 0 into buf 0 + q-segment stats
  BUILD_LOAD(0);
  BUILD_STORE(0, 0);
  if (wv == 0) {
    float sq = 0.f, sqq = 0.f;
#pragma unroll
    for (int it = 0; it < 8; ++it) {
      const float vq = qs[l + (it << 6)];
      sq += vq; sqq += vq * vq;
    }
#pragma unroll
    for (int off = 1; off < 64; off <<= 1) {
      sq += __shfl_xor(sq, off); sqq += __shfl_xor(sqq, off);
    }
    if (l == 0) { misc[0] = sq; misc[1] = sqq; }
  }
  __syncthreads();

  // ---- pipelined chunk loop: wave wv owns cols [wv*32, wv*32+32) ----------
  f32x4 acc[4][2] = {};
  const int ncb = (wv << 5) + (l & 15);
#pragma unroll
  for (int c = 0; c < 4; ++c) {
    if (c < 3) BUILD_LOAD(c + 1);
    const uint4* cbuf = apv + ((c & 1) << 11);
#pragma unroll
    for (int ksl = 0; ksl < 8; ++ksl) {
      const int ks = (c << 3) + ksl;
      bf16x8 bfr[2];
#pragma unroll
      for (int cf = 0; cf < 2; ++cf)
        bfr[cf] = __builtin_bit_cast(bf16x8,
            *(const uint4*)(WT2 + (ks << 14) + ((ncb + (cf << 4)) << 5) + kh));
#pragma unroll
      for (int fr = 0; fr < 4; ++fr) {
        const bf16x8 afr =
            __builtin_bit_cast(bf16x8, cbuf[(ksl << 8) + (fr << 6) + l]);
#pragma unroll
        for (int cf = 0; cf < 2; ++cf)
          acc[fr][cf] = __builtin_amdgcn_mfma_f32_16x16x32_bf16(
              afr, bfr[cf], acc[fr][cf], 0, 0, 0);
      }
    }
    if (c == 0) BUILD_STORE(1, 1);
    if (c == 1) BUILD_STORE(2, 0);
    if (c == 2) {
      BUILD_STORE(3, 1);
      s1a += __shfl_xor(s1a, 16); s1a += __shfl_xor(s1a, 32);
      s2a += __shfl_xor(s2a, 16); s2a += __shfl_xor(s2a, 32);
      if ((l >> 4) == 0) {
        atomicAdd(&s1_s[rloc], s1a);
        atomicAdd(&s2_s[rloc], s2a);
      }
    }
    __syncthreads();
  }
#undef BUILD_LOAD
#undef BUILD_STORE

  // ---- epilogue: LN-fold + gelu + dot(rw2) -> per-row relevance -----------
  {
    const float sqt = misc[0], sqqt = misc[1];
    float yqv[2], s1c[2], b1c[2], w2c[2];
#pragma unroll
    for (int cf = 0; cf < 2; ++cf) {
      const int n = ncb + (cf << 4);
      yqv[cf] = Yq[(q << 9) + n];
      s1c[cf] = S1[n];
      b1c[cf] = B1[n] + rb1[n];
      w2c[cf] = rw2[n];
    }
    const float* yab = Ya + (w << 15) + ncb;
    const int rsub = (l >> 4) << 2;
#pragma unroll
    for (int fr = 0; fr < 4; ++fr) {
#pragma unroll
      for (int j = 0; j < 4; ++j) {
        const int r = (fr << 4) + rsub + j;
        const float s1r = s1_s[r] + sqt;
        const float s2r = s2_s[r] + sqqt;
        const float mu = s1r * (1.0f / 2048.0f);
        const float rs = rsqrtf(s2r * (1.0f / 2048.0f) - mu * mu + 1e-5f);
        float rp = 0.f;
#pragma unroll
        for (int cf = 0; cf < 2; ++cf) {
          const float ya = yab[(r << 9) + (cf << 4)];
          const float hp = rs * (acc[fr][cf][j] + ya + yqv[cf] - mu * s1c[cf]) + b1c[cf];
          rp += gelu_fast(hp) * w2c[cf];
        }
        rp += __shfl_xor(rp, 1); rp += __shfl_xor(rp, 2);
        rp += __shfl_xor(rp, 4); rp += __shfl_xor(rp, 8);
        if ((l & 15) == 0) atomicAdd(&rel_s[r], rp);
      }
    }
  }
  __syncthreads();

  // ---- softmax over atoms + entropy (wave 0)
  if (tid < 64) {
    const float relv = rel_s[tid] + rb2[0];
    const float x = logf(fmaxf(cmass[(w << 6) + tid], 1e-8f)) + relv;
    float m = x;
#pragma unroll
    for (int off = 1; off < 64; off <<= 1) m = fmaxf(m, __shfl_xor(m, off));
    const float p = expf(x - m);
    float s = p;
#pragma unroll
    for (int off = 1; off < 64; off <<= 1) s += __shfl_xor(s, off);
    float mix = p / fmaxf(s, 1e-8f);
    float s2 = mix;
#pragma unroll
    for (int off = 1; off < 64; off <<= 1) s2 += __shfl_xor(s2, off);
    mix = mix / fmaxf(s2, 1e-8f);
    const float et = -mix * logf(fmaxf(mix, 1e-8f));
    float ent = et;
#pragma unroll
    for (int off = 1; off < 64; off <<= 1) ent += __shfl_xor(ent, off);
    out[(blockIdx.x << 6) + tid] = mix;                 // mixed[q][w][a]
    if (tid == 0) out[65536 + blockIdx.x] = ent;        // entropy[q][w]
  }
}

// ---------------------------------------------------------------------------
extern "C" void kernel_launch(void* const* d_in, const int* in_sizes, int n_in,
                              void* d_out, int out_size, void* d_ws, size_t ws_size,
                              hipStream_t stream) {
  (void)in_sizes; (void)n_in; (void)out_size; (void)ws_size;
  const float* q_atoms = (const float*)d_in[0];
  const float* q_mass  = (const float*)d_in[1];
  const float* c_atoms = (const float*)d_in[2];
  const float* c_mass  = (const float*)d_in[3];
  const float* c_sum   = (const float*)d_in[4];
  const float* e_ctx   = (const float*)d_in[5];
  const float* qg  = (const float*)d_in[6];  const float* qb  = (const float*)d_in[7];
  const float* qw1 = (const float*)d_in[8];  const float* qb1 = (const float*)d_in[9];
  const float* qw2 = (const float*)d_in[10]; const float* qb2 = (const float*)d_in[11];
  const float* ag  = (const float*)d_in[12]; const float* ab  = (const float*)d_in[13];
  const float* aw1 = (const float*)d_in[14]; const float* ab1 = (const float*)d_in[15];
  const float* aw2 = (const float*)d_in[16]; const float* ab2 = (const float*)d_in[17];
  const float* cg  = (const float*)d_in[18]; const float* cb  = (const float*)d_in[19];
  const float* cw1 = (const float*)d_in[20]; const float* cb1 = (const float*)d_in[21];
  const float* cw2 = (const float*)d_in[22]; const float* cb2 = (const float*)d_in[23];
  const float* rg  = (const float*)d_in[24]; const float* rb  = (const float*)d_in[25];
  const float* rw1 = (const float*)d_in[26]; const float* rb1 = (const float*)d_in[27];
  const float* rw2 = (const float*)d_in[28]; const float* rb2 = (const float*)d_in[29];

  float* ws = (float*)d_ws;
  float* out = (float*)d_out;

  hipMemsetAsync(ws + OFF_S1, 0, 1024 * sizeof(float), stream);  // S1+B1
  pre0_kernel<<<928, 512, 0, stream>>>(q_atoms, q_mass, c_atoms, c_sum, e_ctx,
                                       qg, qb, ag, ab, cg, cb, rw1, rg, rb,
                                       aw1, qw1, cw1, aw2, qw2, cw2, ws);
  gemm_kernel<1><<<36, 256, 0, stream>>>(ws, ab1, qb1, cb1, rg);
  gemm_kernel<2><<<36, 256, 0, stream>>>(ws, ab2, qb2, cb2, rg);
  gemm_kernel<3><<<34, 256, 0, stream>>>(ws, nullptr, nullptr, nullptr, rg);

  static const size_t MAIN_SMEM = 5120 + 65536;  // 70656 B
  hipFuncSetAttribute((const void*)main_kernel,
                      hipFuncAttributeMaxDynamicSharedMemorySize, (int)MAIN_SMEM);
  main_kernel<<<1024, 1024, MAIN_SMEM, stream>>>(
      ws + OFF_AHH, ws + OFF_QH, ws + OFF_CHH,
      (const ushort_t*)(ws + OFF_WT2), ws + OFF_YA, ws + OFF_YQ,
      ws + OFF_S1, ws + OFF_B1, rb1, rw2, rb2, c_mass, out);
}